// Round 1
// baseline (863.094 us; speedup 1.0000x reference)
//
#include <hip/hip_runtime.h>
#include <hip/hip_bf16.h>

#define N_NODES 50000
#define N_EDGES 800000
#define NUM_GRAPHS 512
#define D 64
#define BN_EPS 1e-5f

// ---------------- init: agg = x (copy), zero BN accumulators ----------------
__global__ __launch_bounds__(256) void k_init(const float* __restrict__ x,
                                              float* __restrict__ agg,
                                              float* __restrict__ bnacc /*128 floats*/) {
    int i = blockIdx.x * 256 + threadIdx.x;           // 800000 float4s exactly
    const float4* xs = (const float4*)x;
    float4* as = (float4*)agg;
    as[i] = xs[i];
    if (blockIdx.x == 0 && threadIdx.x < 128) bnacc[threadIdx.x] = 0.0f;
}

// ---------------- edge scatter: agg[dst] += x[src] (atomic) ----------------
__global__ __launch_bounds__(256) void k_scatter(const int* __restrict__ ei,
                                                 const float* __restrict__ x,
                                                 float* __restrict__ agg) {
    int t = blockIdx.x * 256 + threadIdx.x;           // 12.8M = E*16 exactly
    int e = t >> 4;
    int q = t & 15;
    int s = ei[e];
    int d = ei[N_EDGES + e];
    float4 v = *(const float4*)(x + (size_t)s * D + q * 4);
    float* ap = agg + (size_t)d * D + q * 4;
    atomicAdd(ap + 0, v.x);
    atomicAdd(ap + 1, v.y);
    atomicAdd(ap + 2, v.z);
    atomicAdd(ap + 3, v.w);
}

// ---------------- GEMM1: hT[c][r] = agg[r][:] @ W1[:,c] + b1[c] ----------------
__global__ __launch_bounds__(256) void k_gemm1(const float* __restrict__ agg,
                                               const float* __restrict__ W1,
                                               const float* __restrict__ b1,
                                               float* __restrict__ hT) {
    int r = blockIdx.x * 256 + threadIdx.x;
    if (r >= N_NODES) return;
    float row[D];
#pragma unroll
    for (int k4 = 0; k4 < D / 4; k4++) {
        float4 v = *(const float4*)(agg + (size_t)r * D + k4 * 4);
        row[k4 * 4 + 0] = v.x; row[k4 * 4 + 1] = v.y;
        row[k4 * 4 + 2] = v.z; row[k4 * 4 + 3] = v.w;
    }
    for (int c4 = 0; c4 < D / 4; c4++) {
        float acc[4];
#pragma unroll
        for (int j = 0; j < 4; j++) acc[j] = b1[c4 * 4 + j];
#pragma unroll
        for (int k = 0; k < D; k++) {
#pragma unroll
            for (int j = 0; j < 4; j++)
                acc[j] += row[k] * W1[k * D + c4 * 4 + j];   // wave-uniform -> SGPR
        }
#pragma unroll
        for (int j = 0; j < 4; j++)
            hT[(size_t)(c4 * 4 + j) * N_NODES + r] = acc[j]; // coalesced
    }
}

// ---------------- BN stats: per-feature sum & sumsq over hT rows ----------------
__global__ __launch_bounds__(256) void k_bnstats(const float* __restrict__ hT,
                                                 float* __restrict__ bnsum,
                                                 float* __restrict__ bnsq) {
    __shared__ float ls[256], lq[256];
    int c = blockIdx.y;
    const float* p = hT + (size_t)c * N_NODES;
    float s = 0.f, q = 0.f;
    for (int i = blockIdx.x * 256 + threadIdx.x; i < N_NODES; i += 256 * gridDim.x) {
        float v = p[i];
        s += v; q += v * v;
    }
    int t = threadIdx.x;
    ls[t] = s; lq[t] = q;
    __syncthreads();
    for (int off = 128; off; off >>= 1) {
        if (t < off) { ls[t] += ls[t + off]; lq[t] += lq[t + off]; }
        __syncthreads();
    }
    if (t == 0) { atomicAdd(&bnsum[c], ls[0]); atomicAdd(&bnsq[c], lq[0]); }
}

// ---------------- BN finalize: fold into scale/shift ----------------
__global__ void k_bnfinal(const float* __restrict__ bnsum, const float* __restrict__ bnsq,
                          const float* __restrict__ gamma, const float* __restrict__ beta,
                          float* __restrict__ bnscale, float* __restrict__ bnshift) {
    int c = threadIdx.x;  // 64
    float mean = bnsum[c] * (1.0f / N_NODES);
    float var  = bnsq[c] * (1.0f / N_NODES) - mean * mean;
    float rstd = rsqrtf(var + BN_EPS);
    float sc = gamma[c] * rstd;
    bnscale[c] = sc;
    bnshift[c] = beta[c] - mean * sc;
}

// ---------------- GEMM2: h2T = relu( relu(bn(h)) @ W2 + b2 )^T ----------------
__global__ __launch_bounds__(256) void k_gemm2(const float* __restrict__ hT,
                                               const float* __restrict__ bnscale,
                                               const float* __restrict__ bnshift,
                                               const float* __restrict__ W2,
                                               const float* __restrict__ b2,
                                               float* __restrict__ h2T) {
    int r = blockIdx.x * 256 + threadIdx.x;
    if (r >= N_NODES) return;
    float row[D];
#pragma unroll
    for (int k = 0; k < D; k++) {
        float v = hT[(size_t)k * N_NODES + r];         // coalesced
        row[k] = fmaxf(v * bnscale[k] + bnshift[k], 0.0f);
    }
    for (int c4 = 0; c4 < D / 4; c4++) {
        float acc[4];
#pragma unroll
        for (int j = 0; j < 4; j++) acc[j] = b2[c4 * 4 + j];
#pragma unroll
        for (int k = 0; k < D; k++) {
#pragma unroll
            for (int j = 0; j < 4; j++)
                acc[j] += row[k] * W2[k * D + c4 * 4 + j];
        }
#pragma unroll
        for (int j = 0; j < 4; j++)
            h2T[(size_t)(c4 * 4 + j) * N_NODES + r] = fmaxf(acc[j], 0.0f);
    }
}

// ---------------- pooling: per-graph add & max over sorted batch ----------------
__device__ __forceinline__ int lower_bound(const int* __restrict__ b, int v) {
    int lo = 0, hi = N_NODES;
    while (lo < hi) {
        int m = (lo + hi) >> 1;
        if (b[m] < v) lo = m + 1; else hi = m;
    }
    return lo;
}

__global__ __launch_bounds__(64) void k_pool(const float* __restrict__ h2T,
                                             const int* __restrict__ batch,
                                             float* __restrict__ g) {
    int gi = blockIdx.x;
    int c = threadIdx.x;
    int s0 = lower_bound(batch, gi);       // uniform across wave -> scalar path
    int s1 = lower_bound(batch, gi + 1);
    const float* p = h2T + (size_t)c * N_NODES;
    float sm = 0.0f, mx = 0.0f;            // values are post-ReLU (>=0), so 0-init max is exact
    for (int n = s0; n < s1; n++) {
        float v = p[n];
        sm += v;
        mx = fmaxf(mx, v);
    }
    g[gi * 128 + c] = sm;
    g[gi * 128 + 64 + c] = mx;
}

// ---------------- head: relu(g @ Wl1 + bl1) @ Wl2 + bl2; sigmoid ----------------
__global__ __launch_bounds__(128) void k_head(const float* __restrict__ g,
                                              const float* __restrict__ Wl1,
                                              const float* __restrict__ bl1,
                                              const float* __restrict__ Wl2,
                                              const float* __restrict__ bl2,
                                              float* __restrict__ out) {
    __shared__ float gv[128];
    __shared__ float red[2];
    int gi = blockIdx.x;
    int t = threadIdx.x;
    gv[t] = g[gi * 128 + t];
    __syncthreads();
    float acc = bl1[t];
#pragma unroll
    for (int k = 0; k < 128; k++)
        acc += gv[k] * Wl1[k * 128 + t];   // gv broadcast, Wl1 coalesced
    acc = fmaxf(acc, 0.0f);
    float part = acc * Wl2[t];
    for (int off = 32; off; off >>= 1) part += __shfl_down(part, off);  // wave64 reduce
    if ((t & 63) == 0) red[t >> 6] = part;
    __syncthreads();
    if (t == 0) {
        float logit = red[0] + red[1] + bl2[0];
        out[gi] = 1.0f / (1.0f + expf(-logit));
        out[NUM_GRAPHS + gi] = logit;
    }
}

extern "C" void kernel_launch(void* const* d_in, const int* in_sizes, int n_in,
                              void* d_out, int out_size, void* d_ws, size_t ws_size,
                              hipStream_t stream) {
    const float* x     = (const float*)d_in[0];
    const int*   ei    = (const int*)d_in[1];
    const int*   batch = (const int*)d_in[2];
    const float* W1    = (const float*)d_in[3];
    const float* b1    = (const float*)d_in[4];
    const float* gamma = (const float*)d_in[5];
    const float* beta  = (const float*)d_in[6];
    const float* W2    = (const float*)d_in[7];
    const float* b2    = (const float*)d_in[8];
    const float* Wl1   = (const float*)d_in[9];
    const float* bl1   = (const float*)d_in[10];
    const float* Wl2   = (const float*)d_in[11];
    const float* bl2   = (const float*)d_in[12];
    float* out = (float*)d_out;

    float* ws = (float*)d_ws;
    float* agg    = ws;                         // [N][64]  (12.8 MB)
    float* hT     = agg + (size_t)N_NODES * D;  // [64][N]  (12.8 MB)
    float* gbuf   = hT + (size_t)N_NODES * D;   // [512][128]
    float* bnsum  = gbuf + NUM_GRAPHS * 128;    // 64
    float* bnsq   = bnsum + 64;                 // 64
    float* bnscale= bnsq + 64;                  // 64
    float* bnshift= bnscale + 64;               // 64
    float* h2T    = agg;                        // alias: agg dead after gemm1

    k_init<<<(N_NODES * D / 4 + 255) / 256, 256, 0, stream>>>(x, agg, bnsum);
    k_scatter<<<(N_EDGES * 16) / 256, 256, 0, stream>>>(ei, x, agg);
    k_gemm1<<<(N_NODES + 255) / 256, 256, 0, stream>>>(agg, W1, b1, hT);
    k_bnstats<<<dim3(8, 64), 256, 0, stream>>>(hT, bnsum, bnsq);
    k_bnfinal<<<1, 64, 0, stream>>>(bnsum, bnsq, gamma, beta, bnscale, bnshift);
    k_gemm2<<<(N_NODES + 255) / 256, 256, 0, stream>>>(hT, bnscale, bnshift, W2, b2, h2T);
    k_pool<<<NUM_GRAPHS, 64, 0, stream>>>(h2T, batch, gbuf);
    k_head<<<NUM_GRAPHS, 128, 0, stream>>>(gbuf, Wl1, bl1, Wl2, bl2, out);
}

// Round 2
// 413.381 us; speedup vs baseline: 2.0879x; 2.0879x over previous
//
#include <hip/hip_runtime.h>
#include <hip/hip_bf16.h>

#define N_NODES 50000
#define N_EDGES 800000
#define NUM_GRAPHS 512
#define D 64
#define BN_EPS 1e-5f

// ---------------- zero: deg counters + BN accumulators ----------------
__global__ __launch_bounds__(256) void k_zero(int* __restrict__ deg,
                                              float* __restrict__ bnacc /*128 floats*/) {
    int i = blockIdx.x * 256 + threadIdx.x;
    if (i < N_NODES) deg[i] = 0;
    if (blockIdx.x == 0 && threadIdx.x < 128) bnacc[threadIdx.x] = 0.0f;
}

// ---------------- histogram of destination degree ----------------
__global__ __launch_bounds__(256) void k_hist(const int* __restrict__ ei,
                                              int* __restrict__ deg) {
    int e = blockIdx.x * 256 + threadIdx.x;
    if (e < N_EDGES) atomicAdd(&deg[ei[N_EDGES + e]], 1);
}

// ---------------- single-block exclusive scan over 50000 degrees ----------------
#define SCAN_T 1024
#define SCAN_CHUNK 49   // 1024*49 = 50176 >= 50000
__global__ __launch_bounds__(SCAN_T) void k_scan(const int* __restrict__ deg,
                                                 int* __restrict__ offs,
                                                 int* __restrict__ cursor) {
    __shared__ int part[SCAN_T];
    int t = threadIdx.x;
    int lo = t * SCAN_CHUNK;
    int hi = min(lo + SCAN_CHUNK, N_NODES);
    int s = 0;
    for (int i = lo; i < hi; i++) s += deg[i];
    part[t] = s;
    __syncthreads();
    for (int off = 1; off < SCAN_T; off <<= 1) {
        int v = part[t];
        int u = (t >= off) ? part[t - off] : 0;
        __syncthreads();
        part[t] = v + u;
        __syncthreads();
    }
    int run = (t == 0) ? 0 : part[t - 1];   // exclusive prefix of this chunk
    for (int i = lo; i < hi; i++) {
        offs[i] = run;
        cursor[i] = run;
        run += deg[i];
    }
    if (t == 0) offs[N_NODES] = N_EDGES;
}

// ---------------- bucket reorder: esrc grouped by dst ----------------
__global__ __launch_bounds__(256) void k_reorder(const int* __restrict__ ei,
                                                 int* __restrict__ cursor,
                                                 int* __restrict__ esrc) {
    int e = blockIdx.x * 256 + threadIdx.x;
    if (e < N_EDGES) {
        int s = ei[e];
        int d = ei[N_EDGES + e];
        int p = atomicAdd(&cursor[d], 1);
        esrc[p] = s;
    }
}

// ---------------- gather-sum: agg[n] = x[n] + sum_{e: dst=n} x[src_e] ----------------
__global__ __launch_bounds__(256) void k_gather(const float* __restrict__ x,
                                                const int* __restrict__ offs,
                                                const int* __restrict__ esrc,
                                                float* __restrict__ agg) {
    int wid = (blockIdx.x * 256 + threadIdx.x) >> 6;  // wave id = node id
    int c = threadIdx.x & 63;                          // lane = feature
    if (wid >= N_NODES) return;
    int base = offs[wid];
    int end = offs[wid + 1];
    float acc = x[(size_t)wid * D + c];
    int i = base;
    for (; i + 3 < end; i += 4) {                      // unroll 4: independent loads in flight
        int s0 = esrc[i], s1 = esrc[i + 1], s2 = esrc[i + 2], s3 = esrc[i + 3];
        float v0 = x[(size_t)s0 * D + c];
        float v1 = x[(size_t)s1 * D + c];
        float v2 = x[(size_t)s2 * D + c];
        float v3 = x[(size_t)s3 * D + c];
        acc += v0; acc += v1; acc += v2; acc += v3;
    }
    for (; i < end; i++) acc += x[(size_t)esrc[i] * D + c];
    agg[(size_t)wid * D + c] = acc;                    // coalesced
}

// ---------------- GEMM1: hT[c][r] = agg[r][:] @ W1[:,c] + b1[c] ----------------
__global__ __launch_bounds__(256) void k_gemm1(const float* __restrict__ agg,
                                               const float* __restrict__ W1,
                                               const float* __restrict__ b1,
                                               float* __restrict__ hT) {
    int r = blockIdx.x * 256 + threadIdx.x;
    if (r >= N_NODES) return;
    float row[D];
#pragma unroll
    for (int k4 = 0; k4 < D / 4; k4++) {
        float4 v = *(const float4*)(agg + (size_t)r * D + k4 * 4);
        row[k4 * 4 + 0] = v.x; row[k4 * 4 + 1] = v.y;
        row[k4 * 4 + 2] = v.z; row[k4 * 4 + 3] = v.w;
    }
    for (int c4 = 0; c4 < D / 4; c4++) {
        float acc[4];
#pragma unroll
        for (int j = 0; j < 4; j++) acc[j] = b1[c4 * 4 + j];
#pragma unroll
        for (int k = 0; k < D; k++) {
#pragma unroll
            for (int j = 0; j < 4; j++)
                acc[j] += row[k] * W1[k * D + c4 * 4 + j];   // wave-uniform -> SGPR
        }
#pragma unroll
        for (int j = 0; j < 4; j++)
            hT[(size_t)(c4 * 4 + j) * N_NODES + r] = acc[j]; // coalesced
    }
}

// ---------------- BN stats: per-feature sum & sumsq over hT rows ----------------
__global__ __launch_bounds__(256) void k_bnstats(const float* __restrict__ hT,
                                                 float* __restrict__ bnsum,
                                                 float* __restrict__ bnsq) {
    __shared__ float ls[256], lq[256];
    int c = blockIdx.y;
    const float* p = hT + (size_t)c * N_NODES;
    float s = 0.f, q = 0.f;
    for (int i = blockIdx.x * 256 + threadIdx.x; i < N_NODES; i += 256 * gridDim.x) {
        float v = p[i];
        s += v; q += v * v;
    }
    int t = threadIdx.x;
    ls[t] = s; lq[t] = q;
    __syncthreads();
    for (int off = 128; off; off >>= 1) {
        if (t < off) { ls[t] += ls[t + off]; lq[t] += lq[t + off]; }
        __syncthreads();
    }
    if (t == 0) { atomicAdd(&bnsum[c], ls[0]); atomicAdd(&bnsq[c], lq[0]); }
}

// ---------------- BN finalize: fold into scale/shift ----------------
__global__ void k_bnfinal(const float* __restrict__ bnsum, const float* __restrict__ bnsq,
                          const float* __restrict__ gamma, const float* __restrict__ beta,
                          float* __restrict__ bnscale, float* __restrict__ bnshift) {
    int c = threadIdx.x;  // 64
    float mean = bnsum[c] * (1.0f / N_NODES);
    float var  = bnsq[c] * (1.0f / N_NODES) - mean * mean;
    float rstd = rsqrtf(var + BN_EPS);
    float sc = gamma[c] * rstd;
    bnscale[c] = sc;
    bnshift[c] = beta[c] - mean * sc;
}

// ---------------- GEMM2: h2T = relu( relu(bn(h)) @ W2 + b2 )^T ----------------
__global__ __launch_bounds__(256) void k_gemm2(const float* __restrict__ hT,
                                               const float* __restrict__ bnscale,
                                               const float* __restrict__ bnshift,
                                               const float* __restrict__ W2,
                                               const float* __restrict__ b2,
                                               float* __restrict__ h2T) {
    int r = blockIdx.x * 256 + threadIdx.x;
    if (r >= N_NODES) return;
    float row[D];
#pragma unroll
    for (int k = 0; k < D; k++) {
        float v = hT[(size_t)k * N_NODES + r];         // coalesced
        row[k] = fmaxf(v * bnscale[k] + bnshift[k], 0.0f);
    }
    for (int c4 = 0; c4 < D / 4; c4++) {
        float acc[4];
#pragma unroll
        for (int j = 0; j < 4; j++) acc[j] = b2[c4 * 4 + j];
#pragma unroll
        for (int k = 0; k < D; k++) {
#pragma unroll
            for (int j = 0; j < 4; j++)
                acc[j] += row[k] * W2[k * D + c4 * 4 + j];
        }
#pragma unroll
        for (int j = 0; j < 4; j++)
            h2T[(size_t)(c4 * 4 + j) * N_NODES + r] = fmaxf(acc[j], 0.0f);
    }
}

// ---------------- pooling: per-graph add & max over sorted batch ----------------
__device__ __forceinline__ int lower_bound(const int* __restrict__ b, int v) {
    int lo = 0, hi = N_NODES;
    while (lo < hi) {
        int m = (lo + hi) >> 1;
        if (b[m] < v) lo = m + 1; else hi = m;
    }
    return lo;
}

__global__ __launch_bounds__(64) void k_pool(const float* __restrict__ h2T,
                                             const int* __restrict__ batch,
                                             float* __restrict__ g) {
    int gi = blockIdx.x;
    int c = threadIdx.x;
    int s0 = lower_bound(batch, gi);
    int s1 = lower_bound(batch, gi + 1);
    const float* p = h2T + (size_t)c * N_NODES;
    float sm = 0.0f, mx = 0.0f;            // post-ReLU values >= 0, 0-init max exact
    for (int n = s0; n < s1; n++) {
        float v = p[n];
        sm += v;
        mx = fmaxf(mx, v);
    }
    g[gi * 128 + c] = sm;
    g[gi * 128 + 64 + c] = mx;
}

// ---------------- head: relu(g @ Wl1 + bl1) @ Wl2 + bl2; sigmoid ----------------
__global__ __launch_bounds__(128) void k_head(const float* __restrict__ g,
                                              const float* __restrict__ Wl1,
                                              const float* __restrict__ bl1,
                                              const float* __restrict__ Wl2,
                                              const float* __restrict__ bl2,
                                              float* __restrict__ out) {
    __shared__ float gv[128];
    __shared__ float red[2];
    int gi = blockIdx.x;
    int t = threadIdx.x;
    gv[t] = g[gi * 128 + t];
    __syncthreads();
    float acc = bl1[t];
#pragma unroll
    for (int k = 0; k < 128; k++)
        acc += gv[k] * Wl1[k * 128 + t];
    acc = fmaxf(acc, 0.0f);
    float part = acc * Wl2[t];
    for (int off = 32; off; off >>= 1) part += __shfl_down(part, off);
    if ((t & 63) == 0) red[t >> 6] = part;
    __syncthreads();
    if (t == 0) {
        float logit = red[0] + red[1] + bl2[0];
        out[gi] = 1.0f / (1.0f + expf(-logit));
        out[NUM_GRAPHS + gi] = logit;
    }
}

extern "C" void kernel_launch(void* const* d_in, const int* in_sizes, int n_in,
                              void* d_out, int out_size, void* d_ws, size_t ws_size,
                              hipStream_t stream) {
    const float* x     = (const float*)d_in[0];
    const int*   ei    = (const int*)d_in[1];
    const int*   batch = (const int*)d_in[2];
    const float* W1    = (const float*)d_in[3];
    const float* b1    = (const float*)d_in[4];
    const float* gamma = (const float*)d_in[5];
    const float* beta  = (const float*)d_in[6];
    const float* W2    = (const float*)d_in[7];
    const float* b2    = (const float*)d_in[8];
    const float* Wl1   = (const float*)d_in[9];
    const float* bl1   = (const float*)d_in[10];
    const float* Wl2   = (const float*)d_in[11];
    const float* bl2   = (const float*)d_in[12];
    float* out = (float*)d_out;

    float* ws = (float*)d_ws;
    float* agg    = ws;                         // [N][64]  (12.8 MB)
    float* hT     = agg + (size_t)N_NODES * D;  // [64][N]  (12.8 MB)
    float* gbuf   = hT + (size_t)N_NODES * D;   // [512][128]
    float* bnsum  = gbuf + NUM_GRAPHS * 128;    // 64
    float* bnsq   = bnsum + 64;                 // 64
    float* bnscale= bnsq + 64;                  // 64
    float* bnshift= bnscale + 64;               // 64
    int*   deg    = (int*)(bnshift + 64);       // [N]
    int*   offs   = deg + N_NODES;              // [N+1]
    int*   cursor = offs + N_NODES + 1;         // [N]
    int*   esrc   = cursor + N_NODES;           // [E]
    float* h2T    = agg;                        // alias: agg dead after gemm1

    k_zero<<<(N_NODES + 255) / 256, 256, 0, stream>>>(deg, bnsum);
    k_hist<<<(N_EDGES + 255) / 256, 256, 0, stream>>>(ei, deg);
    k_scan<<<1, SCAN_T, 0, stream>>>(deg, offs, cursor);
    k_reorder<<<(N_EDGES + 255) / 256, 256, 0, stream>>>(ei, cursor, esrc);
    k_gather<<<(N_NODES * 64 + 255) / 256, 256, 0, stream>>>(x, offs, esrc, agg);
    k_gemm1<<<(N_NODES + 255) / 256, 256, 0, stream>>>(agg, W1, b1, hT);
    k_bnstats<<<dim3(8, 64), 256, 0, stream>>>(hT, bnsum, bnsq);
    k_bnfinal<<<1, 64, 0, stream>>>(bnsum, bnsq, gamma, beta, bnscale, bnshift);
    k_gemm2<<<(N_NODES + 255) / 256, 256, 0, stream>>>(hT, bnscale, bnshift, W2, b2, h2T);
    k_pool<<<NUM_GRAPHS, 64, 0, stream>>>(h2T, batch, gbuf);
    k_head<<<NUM_GRAPHS, 128, 0, stream>>>(gbuf, Wl1, bl1, Wl2, bl2, out);
}

// Round 3
// 309.472 us; speedup vs baseline: 2.7889x; 1.3358x over previous
//
#include <hip/hip_runtime.h>
#include <hip/hip_bf16.h>

#define N_NODES 50000
#define N_EDGES 800000
#define NUM_GRAPHS 512
#define D 64
#define BN_EPS 1e-5f

#define SCAN_NBLK 196   // 196*256 = 50176 >= 50000

// ---------------- zero: deg counters + BN accumulators ----------------
__global__ __launch_bounds__(256) void k_zero(int* __restrict__ deg,
                                              float* __restrict__ bnacc /*128 floats*/) {
    int i = blockIdx.x * 256 + threadIdx.x;
    if (i < N_NODES) deg[i] = 0;
    if (blockIdx.x == 0 && threadIdx.x < 128) bnacc[threadIdx.x] = 0.0f;
}

// ---------------- histogram of destination degree ----------------
__global__ __launch_bounds__(256) void k_hist(const int* __restrict__ ei,
                                              int* __restrict__ deg) {
    int e = blockIdx.x * 256 + threadIdx.x;
    if (e < N_EDGES) atomicAdd(&deg[ei[N_EDGES + e]], 1);
}

// ---------------- scan phase 1: per-block sums ----------------
__global__ __launch_bounds__(256) void k_scan1(const int* __restrict__ deg,
                                               int* __restrict__ partials) {
    __shared__ int sm[256];
    int t = threadIdx.x;
    int i = blockIdx.x * 256 + t;
    sm[t] = (i < N_NODES) ? deg[i] : 0;
    __syncthreads();
    for (int off = 128; off; off >>= 1) {
        if (t < off) sm[t] += sm[t + off];
        __syncthreads();
    }
    if (t == 0) partials[blockIdx.x] = sm[0];
}

// ---------------- scan phase 2: exclusive scan of 196 partials ----------------
__global__ __launch_bounds__(256) void k_scan2(int* __restrict__ partials) {
    __shared__ int sm[256];
    int t = threadIdx.x;
    int v = (t < SCAN_NBLK) ? partials[t] : 0;
    sm[t] = v;
    __syncthreads();
    for (int off = 1; off < 256; off <<= 1) {
        int a = sm[t];
        int u = (t >= off) ? sm[t - off] : 0;
        __syncthreads();
        sm[t] = a + u;
        __syncthreads();
    }
    if (t < SCAN_NBLK) partials[t] = sm[t] - v;   // exclusive
}

// ---------------- scan phase 3: block-local exclusive scan + prefix ----------------
__global__ __launch_bounds__(256) void k_scan3(const int* __restrict__ deg,
                                               const int* __restrict__ partials,
                                               int* __restrict__ offs,
                                               int* __restrict__ cursor) {
    __shared__ int sm[256];
    int t = threadIdx.x;
    int i = blockIdx.x * 256 + t;
    int v = (i < N_NODES) ? deg[i] : 0;
    sm[t] = v;
    __syncthreads();
    for (int off = 1; off < 256; off <<= 1) {
        int a = sm[t];
        int u = (t >= off) ? sm[t - off] : 0;
        __syncthreads();
        sm[t] = a + u;
        __syncthreads();
    }
    if (i < N_NODES) {
        int ex = partials[blockIdx.x] + sm[t] - v;  // exclusive prefix
        offs[i] = ex;
        cursor[i] = ex;
    }
    if (blockIdx.x == 0 && t == 0) offs[N_NODES] = N_EDGES;
}

// ---------------- bucket reorder: esrc grouped by dst ----------------
__global__ __launch_bounds__(256) void k_reorder(const int* __restrict__ ei,
                                                 int* __restrict__ cursor,
                                                 int* __restrict__ esrc) {
    int e = blockIdx.x * 256 + threadIdx.x;
    if (e < N_EDGES) {
        int s = ei[e];
        int d = ei[N_EDGES + e];
        int p = atomicAdd(&cursor[d], 1);
        esrc[p] = s;
    }
}

// ---------------- gather-sum: agg[n] = x[n] + sum_{e: dst=n} x[src_e] ----------------
__global__ __launch_bounds__(256) void k_gather(const float* __restrict__ x,
                                                const int* __restrict__ offs,
                                                const int* __restrict__ esrc,
                                                float* __restrict__ agg) {
    int wid = (blockIdx.x * 256 + threadIdx.x) >> 6;  // wave id = node id
    int c = threadIdx.x & 63;                          // lane = feature
    if (wid >= N_NODES) return;
    int base = offs[wid];
    int end = offs[wid + 1];
    float acc = x[(size_t)wid * D + c];
    int i = base;
    for (; i + 3 < end; i += 4) {
        int s0 = esrc[i], s1 = esrc[i + 1], s2 = esrc[i + 2], s3 = esrc[i + 3];
        float v0 = x[(size_t)s0 * D + c];
        float v1 = x[(size_t)s1 * D + c];
        float v2 = x[(size_t)s2 * D + c];
        float v3 = x[(size_t)s3 * D + c];
        acc += v0; acc += v1; acc += v2; acc += v3;
    }
    for (; i < end; i++) acc += x[(size_t)esrc[i] * D + c];
    agg[(size_t)wid * D + c] = acc;                    // coalesced
}

// ---------------- GEMM1: hT[c][r] = agg[r][:] @ W1[:,c] + b1[c] ----------------
__global__ __launch_bounds__(256) void k_gemm1(const float* __restrict__ agg,
                                               const float* __restrict__ W1,
                                               const float* __restrict__ b1,
                                               float* __restrict__ hT) {
    int r = blockIdx.x * 256 + threadIdx.x;
    if (r >= N_NODES) return;
    float row[D];
#pragma unroll
    for (int k4 = 0; k4 < D / 4; k4++) {
        float4 v = *(const float4*)(agg + (size_t)r * D + k4 * 4);
        row[k4 * 4 + 0] = v.x; row[k4 * 4 + 1] = v.y;
        row[k4 * 4 + 2] = v.z; row[k4 * 4 + 3] = v.w;
    }
    for (int c4 = 0; c4 < D / 4; c4++) {
        float acc[4];
#pragma unroll
        for (int j = 0; j < 4; j++) acc[j] = b1[c4 * 4 + j];
#pragma unroll
        for (int k = 0; k < D; k++) {
#pragma unroll
            for (int j = 0; j < 4; j++)
                acc[j] += row[k] * W1[k * D + c4 * 4 + j];   // wave-uniform -> SGPR
        }
#pragma unroll
        for (int j = 0; j < 4; j++)
            hT[(size_t)(c4 * 4 + j) * N_NODES + r] = acc[j]; // coalesced
    }
}

// ---------------- BN stats: per-feature sum & sumsq over hT rows ----------------
__global__ __launch_bounds__(256) void k_bnstats(const float* __restrict__ hT,
                                                 float* __restrict__ bnsum,
                                                 float* __restrict__ bnsq) {
    __shared__ float ls[256], lq[256];
    int c = blockIdx.y;
    const float* p = hT + (size_t)c * N_NODES;
    float s = 0.f, q = 0.f;
    for (int i = blockIdx.x * 256 + threadIdx.x; i < N_NODES; i += 256 * gridDim.x) {
        float v = p[i];
        s += v; q += v * v;
    }
    int t = threadIdx.x;
    ls[t] = s; lq[t] = q;
    __syncthreads();
    for (int off = 128; off; off >>= 1) {
        if (t < off) { ls[t] += ls[t + off]; lq[t] += lq[t + off]; }
        __syncthreads();
    }
    if (t == 0) { atomicAdd(&bnsum[c], ls[0]); atomicAdd(&bnsq[c], lq[0]); }
}

// ---------------- BN finalize: fold into scale/shift ----------------
__global__ void k_bnfinal(const float* __restrict__ bnsum, const float* __restrict__ bnsq,
                          const float* __restrict__ gamma, const float* __restrict__ beta,
                          float* __restrict__ bnscale, float* __restrict__ bnshift) {
    int c = threadIdx.x;  // 64
    float mean = bnsum[c] * (1.0f / N_NODES);
    float var  = bnsq[c] * (1.0f / N_NODES) - mean * mean;
    float rstd = rsqrtf(var + BN_EPS);
    float sc = gamma[c] * rstd;
    bnscale[c] = sc;
    bnshift[c] = beta[c] - mean * sc;
}

// ---------------- GEMM2: h2T = relu( relu(bn(h)) @ W2 + b2 )^T ----------------
__global__ __launch_bounds__(256) void k_gemm2(const float* __restrict__ hT,
                                               const float* __restrict__ bnscale,
                                               const float* __restrict__ bnshift,
                                               const float* __restrict__ W2,
                                               const float* __restrict__ b2,
                                               float* __restrict__ h2T) {
    int r = blockIdx.x * 256 + threadIdx.x;
    if (r >= N_NODES) return;
    float row[D];
#pragma unroll
    for (int k = 0; k < D; k++) {
        float v = hT[(size_t)k * N_NODES + r];         // coalesced
        row[k] = fmaxf(v * bnscale[k] + bnshift[k], 0.0f);
    }
    for (int c4 = 0; c4 < D / 4; c4++) {
        float acc[4];
#pragma unroll
        for (int j = 0; j < 4; j++) acc[j] = b2[c4 * 4 + j];
#pragma unroll
        for (int k = 0; k < D; k++) {
#pragma unroll
            for (int j = 0; j < 4; j++)
                acc[j] += row[k] * W2[k * D + c4 * 4 + j];
        }
#pragma unroll
        for (int j = 0; j < 4; j++)
            h2T[(size_t)(c4 * 4 + j) * N_NODES + r] = fmaxf(acc[j], 0.0f);
    }
}

// ---------------- pooling: per-graph add & max over sorted batch ----------------
__device__ __forceinline__ int lower_bound(const int* __restrict__ b, int v) {
    int lo = 0, hi = N_NODES;
    while (lo < hi) {
        int m = (lo + hi) >> 1;
        if (b[m] < v) lo = m + 1; else hi = m;
    }
    return lo;
}

__global__ __launch_bounds__(64) void k_pool(const float* __restrict__ h2T,
                                             const int* __restrict__ batch,
                                             float* __restrict__ g) {
    int gi = blockIdx.x;
    int c = threadIdx.x;
    int s0 = lower_bound(batch, gi);
    int s1 = lower_bound(batch, gi + 1);
    const float* p = h2T + (size_t)c * N_NODES;
    float sm = 0.0f, mx = 0.0f;            // post-ReLU values >= 0, 0-init max exact
    for (int n = s0; n < s1; n++) {
        float v = p[n];
        sm += v;
        mx = fmaxf(mx, v);
    }
    g[gi * 128 + c] = sm;
    g[gi * 128 + 64 + c] = mx;
}

// ---------------- head: relu(g @ Wl1 + bl1) @ Wl2 + bl2; sigmoid ----------------
__global__ __launch_bounds__(128) void k_head(const float* __restrict__ g,
                                              const float* __restrict__ Wl1,
                                              const float* __restrict__ bl1,
                                              const float* __restrict__ Wl2,
                                              const float* __restrict__ bl2,
                                              float* __restrict__ out) {
    __shared__ float gv[128];
    __shared__ float red[2];
    int gi = blockIdx.x;
    int t = threadIdx.x;
    gv[t] = g[gi * 128 + t];
    __syncthreads();
    float acc = bl1[t];
#pragma unroll
    for (int k = 0; k < 128; k++)
        acc += gv[k] * Wl1[k * 128 + t];
    acc = fmaxf(acc, 0.0f);
    float part = acc * Wl2[t];
    for (int off = 32; off; off >>= 1) part += __shfl_down(part, off);
    if ((t & 63) == 0) red[t >> 6] = part;
    __syncthreads();
    if (t == 0) {
        float logit = red[0] + red[1] + bl2[0];
        out[gi] = 1.0f / (1.0f + expf(-logit));
        out[NUM_GRAPHS + gi] = logit;
    }
}

extern "C" void kernel_launch(void* const* d_in, const int* in_sizes, int n_in,
                              void* d_out, int out_size, void* d_ws, size_t ws_size,
                              hipStream_t stream) {
    const float* x     = (const float*)d_in[0];
    const int*   ei    = (const int*)d_in[1];
    const int*   batch = (const int*)d_in[2];
    const float* W1    = (const float*)d_in[3];
    const float* b1    = (const float*)d_in[4];
    const float* gamma = (const float*)d_in[5];
    const float* beta  = (const float*)d_in[6];
    const float* W2    = (const float*)d_in[7];
    const float* b2    = (const float*)d_in[8];
    const float* Wl1   = (const float*)d_in[9];
    const float* bl1   = (const float*)d_in[10];
    const float* Wl2   = (const float*)d_in[11];
    const float* bl2   = (const float*)d_in[12];
    float* out = (float*)d_out;

    float* ws = (float*)d_ws;
    float* agg    = ws;                         // [N][64]  (12.8 MB)
    float* hT     = agg + (size_t)N_NODES * D;  // [64][N]  (12.8 MB)
    float* gbuf   = hT + (size_t)N_NODES * D;   // [512][128]
    float* bnsum  = gbuf + NUM_GRAPHS * 128;    // 64
    float* bnsq   = bnsum + 64;                 // 64
    float* bnscale= bnsq + 64;                  // 64
    float* bnshift= bnscale + 64;               // 64
    int*   deg    = (int*)(bnshift + 64);       // [N]
    int*   offs   = deg + N_NODES;              // [N+1]
    int*   cursor = offs + N_NODES + 1;         // [N]
    int*   esrc   = cursor + N_NODES;           // [E]
    int*   partials = esrc + N_EDGES;           // [256]
    float* h2T    = agg;                        // alias: agg dead after gemm1

    k_zero<<<(N_NODES + 255) / 256, 256, 0, stream>>>(deg, bnsum);
    k_hist<<<(N_EDGES + 255) / 256, 256, 0, stream>>>(ei, deg);
    k_scan1<<<SCAN_NBLK, 256, 0, stream>>>(deg, partials);
    k_scan2<<<1, 256, 0, stream>>>(partials);
    k_scan3<<<SCAN_NBLK, 256, 0, stream>>>(deg, partials, offs, cursor);
    k_reorder<<<(N_EDGES + 255) / 256, 256, 0, stream>>>(ei, cursor, esrc);
    k_gather<<<(N_NODES * 64 + 255) / 256, 256, 0, stream>>>(x, offs, esrc, agg);
    k_gemm1<<<(N_NODES + 255) / 256, 256, 0, stream>>>(agg, W1, b1, hT);
    k_bnstats<<<dim3(8, 64), 256, 0, stream>>>(hT, bnsum, bnsq);
    k_bnfinal<<<1, 64, 0, stream>>>(bnsum, bnsq, gamma, beta, bnscale, bnshift);
    k_gemm2<<<(N_NODES + 255) / 256, 256, 0, stream>>>(hT, bnscale, bnshift, W2, b2, h2T);
    k_pool<<<NUM_GRAPHS, 64, 0, stream>>>(h2T, batch, gbuf);
    k_head<<<NUM_GRAPHS, 128, 0, stream>>>(gbuf, Wl1, bl1, Wl2, bl2, out);
}